// Round 4
// baseline (342.056 us; speedup 1.0000x reference)
//
#include <hip/hip_runtime.h>
#include <hip/hip_bf16.h>

// Problem constants
#define N_TOK 8192
#define INL   512
#define OUTL  512
#define NE    8
#define NI    16

typedef unsigned short ushort_t;
typedef unsigned int   uint_t;
typedef short  short8  __attribute__((ext_vector_type(8)));
typedef float  floatx4 __attribute__((ext_vector_type(4)));

// ---------------- workspace layout (bytes) ----------------
#define WS_S      0u         // float[512]
#define WS_GAM    2048u      // float[8]
#define WS_RGAM   2080u      // float[8]
#define WS_BET    2112u      // float[4096]   : bet_eff[e][d] = bet + gam*b   (ends 18496)
#define WS_SELE   18496u     // int[8192]     : e0 | e1<<8                    (ends 51264)
#define WS_SELW   51264u     // float4[8192]  : {rw0*gam0, rw1*gam1, rw0, rw1}(ends 182336)
#define WS_WT     182336u    // ushort[8*512*512] : W^T bf16 [e][d][l]        (ends 4376640)
#define WS_XBF    4376640u   // ushort[8192*512]  : x in bf16                 (ends 12765248)
#define WS_NEED   12765248u  // full layout incl. xbf
// If ws_size < WS_NEED, xbf is unused and k_gemm converts fp32->bf16 inline.

__device__ __forceinline__ ushort_t f2bf(float f) {
    uint_t b = __float_as_uint(f);
    return (ushort_t)((b + 0x7FFFu + ((b >> 16) & 1u)) >> 16);   // RNE
}
__device__ __forceinline__ uint_t pack2(float a, float b) {
    return (uint_t)f2bf(a) | ((uint_t)f2bf(b) << 16);
}

// ---------------- K1: s[h], gam[e], rgam[e] ----------------
__global__ void k_stats(const float* __restrict__ ins,
                        const float* __restrict__ gamma_w,
                        const float* __restrict__ rmod_w,
                        float* __restrict__ wsS, float* __restrict__ wsGam,
                        float* __restrict__ wsRgam) {
    __shared__ float sS[INL];
    __shared__ float pg[64], pr[64];
    int tid = threadIdx.x;
    for (int h = tid; h < INL; h += 256) {
        float a = 0.f;
        for (int n = 0; n < NI; ++n) a += ins[n * INL + h];
        sS[h] = a;
        wsS[h] = a;
    }
    __syncthreads();
    if (tid < 64) {
        int e = tid & 7, qq = tid >> 3;
        float g = 0.f, r = 0.f;
        for (int j = 0; j < 64; ++j) {
            int h = qq * 64 + j;
            float sv = sS[h];
            g += sv * gamma_w[e * INL + h];
            r += sv * rmod_w[h * NE + e];
        }
        pg[tid] = g; pr[tid] = r;
    }
    __syncthreads();
    if (tid < NE) {
        float g = 0.f, r = 0.f;
        for (int qq = 0; qq < 8; ++qq) { g += pg[qq * 8 + tid]; r += pr[qq * 8 + tid]; }
        wsGam[tid]  = g * (1.f / NI);
        wsRgam[tid] = r * (1.f / NI);
    }
}

// ---------------- K2: bet_eff[e][d] ----------------
__global__ void k_bet(const float* __restrict__ beta_w,
                      const float* __restrict__ expert_b,
                      const float* __restrict__ wsS,
                      const float* __restrict__ wsGam,
                      float* __restrict__ wsBet) {
    __shared__ float red[256];
    int e = blockIdx.y;
    int dBase = blockIdx.x * 32;
    int tid = threadIdx.x;
    int doff = tid & 31, hq = tid >> 5;
    float a = 0.f;
    for (int j = 0; j < 64; ++j) {
        int h = hq * 64 + j;
        a += wsS[h] * beta_w[(e * INL + h) * OUTL + dBase + doff];
    }
    red[tid] = a;
    __syncthreads();
    if (tid < 32) {
        float t = 0.f;
        for (int k = 0; k < 8; ++k) t += red[k * 32 + tid];
        int d = dBase + tid;
        wsBet[e * OUTL + d] = t * (1.f / NI) + wsGam[e] * expert_b[e * OUTL + d];
    }
}

// ---------------- K3: router (fp32) + optional x->bf16 conversion ----------------
__global__ void k_route(const float* __restrict__ x,
                        const float* __restrict__ gate_w,
                        const float* __restrict__ wsGam,
                        const float* __restrict__ wsRgam,
                        int* __restrict__ selE, float4* __restrict__ selW,
                        ushort_t* __restrict__ xbf, int use_xbf) {
    __shared__ float gateT[NE * INL];   // 16 KB, [e][l]
    int tid = threadIdx.x;
    for (int i = 0; i < 16; ++i) {
        int f = tid + 256 * i;
        float v = gate_w[f];
        gateT[(f & 7) * INL + (f >> 3)] = v;
    }
    __syncthreads();

    int w = tid >> 6, lane = tid & 63;
    int t = blockIdx.x * 4 + w;

    float2 xv[4];
    for (int i = 0; i < 4; ++i)
        xv[i] = *(const float2*)(x + (size_t)t * INL + 2 * lane + 128 * i);

    if (use_xbf) {
        uint_t* xb32 = (uint_t*)xbf;
        for (int i = 0; i < 4; ++i)
            xb32[t * 256 + lane + 64 * i] = pack2(xv[i].x, xv[i].y);
    }

    float acc[NE];
    for (int e = 0; e < NE; ++e) acc[e] = 0.f;
    for (int i = 0; i < 4; ++i) {
        int c = 2 * lane + 128 * i;
        for (int e = 0; e < NE; ++e)
            acc[e] += xv[i].x * gateT[e * INL + c] + xv[i].y * gateT[e * INL + c + 1];
    }
    for (int e = 0; e < NE; ++e) {
        float a = acc[e];
        for (int off = 32; off >= 1; off >>= 1) a += __shfl_xor(a, off, 64);
        acc[e] = a;
    }
    float logit[NE];
    for (int e = 0; e < NE; ++e) logit[e] = acc[e] + wsRgam[e];

    // top-2, lowest-index tie-break
    int i0 = 0; float m0 = logit[0];
    for (int e = 1; e < NE; ++e) if (logit[e] > m0) { m0 = logit[e]; i0 = e; }
    int i1 = -1; float m1 = -3.4e38f;
    for (int e = 0; e < NE; ++e) if (e != i0 && logit[e] > m1) { m1 = logit[e]; i1 = e; }

    float S = 0.f;
    for (int e = 0; e < NE; ++e) S += expf(logit[e] - m0);
    float rw0 = 1.0f / S;
    float rw1 = expf(m1 - m0) / S;

    if (lane == 0) {
        selE[t] = i0 | (i1 << 8);
        selW[t] = make_float4(rw0 * wsGam[i0], rw1 * wsGam[i1], rw0, rw1);
    }
}

// ---------------- K4: W [e][l][d] fp32 -> Wt [e][d][l] bf16 ----------------
__global__ void k_wt(const float* __restrict__ expert_w, ushort_t* __restrict__ wt) {
    __shared__ float tile[64][65];
    int e = blockIdx.z;
    int lt = blockIdx.y * 64, dt = blockIdx.x * 64;
    int tid = threadIdx.x;
    int dIdx = tid & 63, lq = tid >> 6;
    for (int i = 0; i < 16; ++i) {
        int l = lq * 16 + i;
        tile[l][dIdx] = expert_w[(e * INL + lt + l) * OUTL + dt + dIdx];
    }
    __syncthreads();
    int lIdx = tid & 63, dq = tid >> 6;
    for (int i = 0; i < 16; ++i) {
        int d = dq * 16 + i;
        wt[(e * OUTL + dt + d) * INL + lt + lIdx] = f2bf(tile[lIdx][d]);
    }
}

// ---------------- K5: DENSE all-expert GEMM with per-expert fold ----------------
// Block = M=64 tokens x N=128 cols. Loops e=0..7; fold acc->comb with per-row
// combine weight. Out written once (no atomics). Bias/beta folded in epilogue.
#define LDP 72   // LDS pitch in bf16 elems
__global__ __launch_bounds__(256, 2)
void k_gemm(const float* __restrict__ x, const ushort_t* __restrict__ xbf,
            const ushort_t* __restrict__ wt,
            const int* __restrict__ selE, const float4* __restrict__ selW,
            const float* __restrict__ wsBet, float* __restrict__ out,
            int use_xbf) {
    int bx = blockIdx.x;
    int rt = bx & 127;                 // token slab: rows rt*64..+64
    int ct = bx >> 7;                  // col slab: ct*128..+128
    __shared__ ushort_t Alds[64 * LDP];    // 9 KB
    __shared__ ushort_t Blds[128 * LDP];   // 18 KB
    __shared__ float wTab[64 * NE];        // combine weight per (row, e)
    __shared__ float2 rTab[64];            // raw {rw0, rw1} per row
    __shared__ int    eTab[64];            // e0 | e1<<8 per row

    int tid = threadIdx.x;
    if (tid < 64) {
        int tok = rt * 64 + tid;
        int es = selE[tok];
        float4 w4 = selW[tok];
        int e0 = es & 255, e1 = es >> 8;
        for (int e = 0; e < NE; ++e)
            wTab[tid * NE + e] = (e == e0) ? w4.x : ((e == e1) ? w4.y : 0.f);
        eTab[tid] = es;
        rTab[tid] = make_float2(w4.z, w4.w);
    }

    int wid = tid >> 6, lane = tid & 63;
    int wm = (wid >> 1) * 32, wn = (wid & 1) * 64;
    int mrow = lane & 15, q8 = (lane >> 4) * 8, qr = (lane >> 4) * 4;

    // staging maps: A rows (tid>>3, +32), col seg (tid&7)*8; B row tid>>1, col (tid&1)*32
    int arow = tid >> 3, acseg = (tid & 7) * 8;
    int br = tid >> 1, bco = (tid & 1) * 32;
    const ushort_t* abase_bf = xbf + (size_t)(rt * 64) * INL;
    const float*    abase_f  = x   + (size_t)(rt * 64) * INL;
    const ushort_t* bbase = wt + (size_t)(ct * 128 + br) * INL + bco;

    floatx4 comb[2][4];
    for (int mt = 0; mt < 2; ++mt)
        for (int nt = 0; nt < 4; ++nt)
            comb[mt][nt] = (floatx4){0.f, 0.f, 0.f, 0.f};

    uint4  pa[2];      // bf16 path prefetch
    float4 paf[4];     // fp32 path prefetch (rows arow, arow+32 : 8 floats each)
    uint4  pb[4];

    // prefetch (e=0, kc=0)
    if (use_xbf) {
        const ushort_t* p = abase_bf + (size_t)arow * INL + acseg;
        pa[0] = *(const uint4*)p;
        pa[1] = *(const uint4*)(p + 32 * INL);
    } else {
        const float* p = abase_f + (size_t)arow * INL + acseg;
        paf[0] = *(const float4*)p;       paf[1] = *(const float4*)(p + 4);
        paf[2] = *(const float4*)(p + 32 * INL); paf[3] = *(const float4*)(p + 32 * INL + 4);
    }
    for (int i = 0; i < 4; ++i) pb[i] = *(const uint4*)(bbase + i * 8);

    __syncthreads();   // tabs ready; LDS still untouched

    for (int e = 0; e < NE; ++e) {
        floatx4 acc[2][4];
        for (int mt = 0; mt < 2; ++mt)
            for (int nt = 0; nt < 4; ++nt)
                acc[mt][nt] = (floatx4){0.f, 0.f, 0.f, 0.f};

        for (int kc = 0; kc < 8; ++kc) {
            if (e | kc) __syncthreads();   // previous tile's frag reads complete
            // store staged tile
            if (use_xbf) {
                *(uint4*)&Alds[arow * LDP + acseg] = pa[0];
                *(uint4*)&Alds[(arow + 32) * LDP + acseg] = pa[1];
            } else {
                uint4 w0, w1;
                w0.x = pack2(paf[0].x, paf[0].y); w0.y = pack2(paf[0].z, paf[0].w);
                w0.z = pack2(paf[1].x, paf[1].y); w0.w = pack2(paf[1].z, paf[1].w);
                w1.x = pack2(paf[2].x, paf[2].y); w1.y = pack2(paf[2].z, paf[2].w);
                w1.z = pack2(paf[3].x, paf[3].y); w1.w = pack2(paf[3].z, paf[3].w);
                *(uint4*)&Alds[arow * LDP + acseg] = w0;
                *(uint4*)&Alds[(arow + 32) * LDP + acseg] = w1;
            }
            *(uint4*)&Blds[br * LDP + bco]      = pb[0];
            *(uint4*)&Blds[br * LDP + bco + 8]  = pb[1];
            *(uint4*)&Blds[br * LDP + bco + 16] = pb[2];
            *(uint4*)&Blds[br * LDP + bco + 24] = pb[3];
            __syncthreads();

            // prefetch next (flies during MFMA)
            int ne = e, nkc = kc + 1;
            if (nkc == 8) { nkc = 0; ne = e + 1; }
            if (ne < NE) {
                if (use_xbf) {
                    const ushort_t* p = abase_bf + (size_t)arow * INL + nkc * 64 + acseg;
                    pa[0] = *(const uint4*)p;
                    pa[1] = *(const uint4*)(p + 32 * INL);
                } else {
                    const float* p = abase_f + (size_t)arow * INL + nkc * 64 + acseg;
                    paf[0] = *(const float4*)p;       paf[1] = *(const float4*)(p + 4);
                    paf[2] = *(const float4*)(p + 32 * INL); paf[3] = *(const float4*)(p + 32 * INL + 4);
                }
                const ushort_t* bsrc = bbase + (size_t)ne * OUTL * INL + nkc * 64;
                for (int i = 0; i < 4; ++i) pb[i] = *(const uint4*)(bsrc + i * 8);
            }

            // compute tile
            for (int ks = 0; ks < 64; ks += 32) {
                short8 af[2], bf[4];
                for (int mt = 0; mt < 2; ++mt)
                    af[mt] = *(const short8*)&Alds[(wm + mt * 16 + mrow) * LDP + ks + q8];
                for (int nt = 0; nt < 4; ++nt)
                    bf[nt] = *(const short8*)&Blds[(wn + nt * 16 + mrow) * LDP + ks + q8];
                for (int mt = 0; mt < 2; ++mt)
                    for (int nt = 0; nt < 4; ++nt)
                        acc[mt][nt] = __builtin_amdgcn_mfma_f32_16x16x32_bf16(
                            af[mt], bf[nt], acc[mt][nt], 0, 0, 0);
            }
        }

        // fold expert e into comb with per-row combine weight
        for (int mt = 0; mt < 2; ++mt) {
            float wv0 = wTab[(wm + mt * 16 + qr + 0) * NE + e];
            float wv1 = wTab[(wm + mt * 16 + qr + 1) * NE + e];
            float wv2 = wTab[(wm + mt * 16 + qr + 2) * NE + e];
            float wv3 = wTab[(wm + mt * 16 + qr + 3) * NE + e];
            for (int nt = 0; nt < 4; ++nt) {
                comb[mt][nt][0] += wv0 * acc[mt][nt][0];
                comb[mt][nt][1] += wv1 * acc[mt][nt][1];
                comb[mt][nt][2] += wv2 * acc[mt][nt][2];
                comb[mt][nt][3] += wv3 * acc[mt][nt][3];
            }
        }
    }

    // epilogue: out = comb + rw0*bet_eff[e0] + rw1*bet_eff[e1], single plain store
    for (int mt = 0; mt < 2; ++mt) {
        for (int ri = 0; ri < 4; ++ri) {
            int row = wm + mt * 16 + qr + ri;
            int tok = rt * 64 + row;
            int es = eTab[row];
            int e0 = es & 255, e1 = es >> 8;
            float2 rv = rTab[row];
            for (int nt = 0; nt < 4; ++nt) {
                int col = ct * 128 + wn + nt * 16 + (lane & 15);
                float bet = rv.x * wsBet[e0 * OUTL + col] + rv.y * wsBet[e1 * OUTL + col];
                out[(size_t)tok * OUTL + col] = comb[mt][nt][ri] + bet;
            }
        }
    }
}

extern "C" void kernel_launch(void* const* d_in, const int* in_sizes, int n_in,
                              void* d_out, int out_size, void* d_ws, size_t ws_size,
                              hipStream_t stream) {
    const float* x        = (const float*)d_in[0];
    const float* ins      = (const float*)d_in[1];
    const float* gate_w   = (const float*)d_in[2];
    const float* expert_w = (const float*)d_in[3];
    const float* expert_b = (const float*)d_in[4];
    const float* gamma_w  = (const float*)d_in[5];
    const float* beta_w   = (const float*)d_in[6];
    const float* rmod_w   = (const float*)d_in[7];
    float* out = (float*)d_out;

    char* ws = (char*)d_ws;
    float*    wsS    = (float*)(ws + WS_S);
    float*    wsGam  = (float*)(ws + WS_GAM);
    float*    wsRgam = (float*)(ws + WS_RGAM);
    float*    wsBet  = (float*)(ws + WS_BET);
    int*      selE   = (int*)(ws + WS_SELE);
    float4*   selW   = (float4*)(ws + WS_SELW);
    ushort_t* wt     = (ushort_t*)(ws + WS_WT);
    ushort_t* xbf    = (ushort_t*)(ws + WS_XBF);

    int use_xbf = (ws_size >= (size_t)WS_NEED) ? 1 : 0;

    // independent: W transpose+convert
    k_wt<<<dim3(8, 8, 8), 256, 0, stream>>>(expert_w, wt);
    // stats -> bet -> route -> gemm (stream-ordered dependencies)
    k_stats<<<1, 256, 0, stream>>>(ins, gamma_w, rmod_w, wsS, wsGam, wsRgam);
    k_bet<<<dim3(16, 8), 256, 0, stream>>>(beta_w, expert_b, wsS, wsGam, wsBet);
    k_route<<<N_TOK / 4, 256, 0, stream>>>(x, gate_w, wsGam, wsRgam, selE, selW, xbf, use_xbf);
    k_gemm<<<512, 256, 0, stream>>>(x, xbf, wt, selE, selW, wsBet, out, use_xbf);
}

// Round 5
// 309.988 us; speedup vs baseline: 1.1034x; 1.1034x over previous
//
#include <hip/hip_runtime.h>
#include <hip/hip_bf16.h>

// Problem constants
#define N_TOK 8192
#define INL   512
#define OUTL  512
#define NE    8
#define NI    16

typedef unsigned short ushort_t;
typedef unsigned int   uint_t;
typedef short  short8  __attribute__((ext_vector_type(8)));
typedef float  floatx4 __attribute__((ext_vector_type(4)));

// ---------------- workspace layout (bytes) ----------------
#define WS_S      0u         // float[512]
#define WS_GAM    2048u      // float[8]
#define WS_RGAM   2080u      // float[8]
#define WS_BET    2112u      // float[4096]   : bet_eff[e][d] = bet + gam*b
#define WS_SELE   18496u     // int[8192]     : e0 | e1<<8
#define WS_SELW   51264u     // float4[8192]  : {rw0*gam0, rw1*gam1, rw0, rw1}
#define WS_WT     182336u    // ushort[8*512*512] : W^T bf16 [e][d][l]  (ends 4376640)

__device__ __forceinline__ ushort_t f2bf(float f) {
    uint_t b = __float_as_uint(f);
    return (ushort_t)((b + 0x7FFFu + ((b >> 16) & 1u)) >> 16);   // RNE
}
__device__ __forceinline__ uint_t pkbf(float a, float b) {
    // a -> low 16, b -> high 16, RNE (v_cvt_pk_bf16_f32 on gfx950)
    __hip_bfloat162 h = __float22bfloat162_rn(make_float2(a, b));
    union { __hip_bfloat162 h2; uint_t u; } cv;
    cv.h2 = h;
    return cv.u;
}

// ---------------- K1: s[h], gam[e], rgam[e] ----------------
__global__ void k_stats(const float* __restrict__ ins,
                        const float* __restrict__ gamma_w,
                        const float* __restrict__ rmod_w,
                        float* __restrict__ wsS, float* __restrict__ wsGam,
                        float* __restrict__ wsRgam) {
    __shared__ float sS[INL];
    __shared__ float pg[64], pr[64];
    int tid = threadIdx.x;
    for (int h = tid; h < INL; h += 256) {
        float a = 0.f;
        for (int n = 0; n < NI; ++n) a += ins[n * INL + h];
        sS[h] = a;
        wsS[h] = a;
    }
    __syncthreads();
    if (tid < 64) {
        int e = tid & 7, qq = tid >> 3;
        float g = 0.f, r = 0.f;
        for (int j = 0; j < 64; ++j) {
            int h = qq * 64 + j;
            float sv = sS[h];
            g += sv * gamma_w[e * INL + h];
            r += sv * rmod_w[h * NE + e];
        }
        pg[tid] = g; pr[tid] = r;
    }
    __syncthreads();
    if (tid < NE) {
        float g = 0.f, r = 0.f;
        for (int qq = 0; qq < 8; ++qq) { g += pg[qq * 8 + tid]; r += pr[qq * 8 + tid]; }
        wsGam[tid]  = g * (1.f / NI);
        wsRgam[tid] = r * (1.f / NI);
    }
}

// ---------------- K2: bet_eff[e][d] ----------------
__global__ void k_bet(const float* __restrict__ beta_w,
                      const float* __restrict__ expert_b,
                      const float* __restrict__ wsS,
                      const float* __restrict__ wsGam,
                      float* __restrict__ wsBet) {
    __shared__ float red[256];
    int e = blockIdx.y;
    int dBase = blockIdx.x * 32;
    int tid = threadIdx.x;
    int doff = tid & 31, hq = tid >> 5;
    float a = 0.f;
    for (int j = 0; j < 64; ++j) {
        int h = hq * 64 + j;
        a += wsS[h] * beta_w[(e * INL + h) * OUTL + dBase + doff];
    }
    red[tid] = a;
    __syncthreads();
    if (tid < 32) {
        float t = 0.f;
        for (int k = 0; k < 8; ++k) t += red[k * 32 + tid];
        int d = dBase + tid;
        wsBet[e * OUTL + d] = t * (1.f / NI) + wsGam[e] * expert_b[e * OUTL + d];
    }
}

// ---------------- K3: router (fp32 logits), top-2, sel tables ----------------
__global__ void k_route(const float* __restrict__ x,
                        const float* __restrict__ gate_w,
                        const float* __restrict__ wsGam,
                        const float* __restrict__ wsRgam,
                        int* __restrict__ selE, float4* __restrict__ selW) {
    __shared__ float gateT[NE * INL];   // 16 KB, [e][l]
    int tid = threadIdx.x;
    for (int i = 0; i < 16; ++i) {
        int f = tid + 256 * i;
        float v = gate_w[f];
        gateT[(f & 7) * INL + (f >> 3)] = v;
    }
    __syncthreads();

    int w = tid >> 6, lane = tid & 63;
    int t = blockIdx.x * 4 + w;

    float2 xv[4];
    for (int i = 0; i < 4; ++i)
        xv[i] = *(const float2*)(x + (size_t)t * INL + 2 * lane + 128 * i);

    float acc[NE];
    for (int e = 0; e < NE; ++e) acc[e] = 0.f;
    for (int i = 0; i < 4; ++i) {
        int c = 2 * lane + 128 * i;
        for (int e = 0; e < NE; ++e)
            acc[e] += xv[i].x * gateT[e * INL + c] + xv[i].y * gateT[e * INL + c + 1];
    }
    for (int e = 0; e < NE; ++e) {
        float a = acc[e];
        for (int off = 32; off >= 1; off >>= 1) a += __shfl_xor(a, off, 64);
        acc[e] = a;
    }
    float logit[NE];
    for (int e = 0; e < NE; ++e) logit[e] = acc[e] + wsRgam[e];

    // top-2, lowest-index tie-break
    int i0 = 0; float m0 = logit[0];
    for (int e = 1; e < NE; ++e) if (logit[e] > m0) { m0 = logit[e]; i0 = e; }
    int i1 = -1; float m1 = -3.4e38f;
    for (int e = 0; e < NE; ++e) if (e != i0 && logit[e] > m1) { m1 = logit[e]; i1 = e; }

    float S = 0.f;
    for (int e = 0; e < NE; ++e) S += expf(logit[e] - m0);
    float rw0 = 1.0f / S;
    float rw1 = expf(m1 - m0) / S;

    if (lane == 0) {
        selE[t] = i0 | (i1 << 8);
        selW[t] = make_float4(rw0 * wsGam[i0], rw1 * wsGam[i1], rw0, rw1);
    }
}

// ---------------- K4: W [e][l][d] fp32 -> Wt [e][d][l] bf16 ----------------
__global__ void k_wt(const float* __restrict__ expert_w, ushort_t* __restrict__ wt) {
    __shared__ float tile[64][65];
    int e = blockIdx.z;
    int lt = blockIdx.y * 64, dt = blockIdx.x * 64;
    int tid = threadIdx.x;
    int dIdx = tid & 63, lq = tid >> 6;
    for (int i = 0; i < 16; ++i) {
        int l = lq * 16 + i;
        tile[l][dIdx] = expert_w[(e * INL + lt + l) * OUTL + dt + dIdx];
    }
    __syncthreads();
    int lIdx = tid & 63, dq = tid >> 6;
    for (int i = 0; i < 16; ++i) {
        int d = dq * 16 + i;
        wt[(e * OUTL + dt + d) * INL + lt + lIdx] = f2bf(tile[lIdx][d]);
    }
}

// ---------------- K5: DENSE all-expert GEMM, combine folded into A-staging ----------
// Block = M=64 tokens x N=128 cols. For expert e, A is staged as
// RNE(w[row][e] * x[row][k]) so ONE accumulator integrates all experts.
// Out written once, no atomics. Bias/beta folded in epilogue.
#define LDP 72   // LDS pitch in bf16 elems
__global__ __launch_bounds__(256, 2)
void k_gemm(const float* __restrict__ x, const ushort_t* __restrict__ wt,
            const int* __restrict__ selE, const float4* __restrict__ selW,
            const float* __restrict__ wsBet, float* __restrict__ out) {
    int bx = blockIdx.x;
    int rt = bx & 127;                 // token slab: rows rt*64..+64
    int ct = bx >> 7;                  // col slab: ct*128..+128
    __shared__ ushort_t Alds[64 * LDP];    // 9 KB
    __shared__ ushort_t Blds[128 * LDP];   // 18 KB
    __shared__ float wTab[64 * NE];        // combine weight per (row, e)
    __shared__ float2 rTab[64];            // raw {rw0, rw1} per row
    __shared__ int    eTab[64];            // e0 | e1<<8 per row

    int tid = threadIdx.x;
    if (tid < 64) {
        int tok = rt * 64 + tid;
        int es = selE[tok];
        float4 w4 = selW[tok];
        int e0 = es & 255, e1 = es >> 8;
        for (int e = 0; e < NE; ++e)
            wTab[tid * NE + e] = (e == e0) ? w4.x : ((e == e1) ? w4.y : 0.f);
        eTab[tid] = es;
        rTab[tid] = make_float2(w4.z, w4.w);
    }

    int wid = tid >> 6, lane = tid & 63;
    int wm = (wid >> 1) * 32, wn = (wid & 1) * 64;
    int mrow = lane & 15, q8 = (lane >> 4) * 8, qr = (lane >> 4) * 4;

    // staging maps: A rows arow & arow+32, 8 fp32 cols each; B row br, 32 bf16 cols
    int arow = tid >> 3, acseg = (tid & 7) * 8;
    int br = tid >> 1, bco = (tid & 1) * 32;
    const float*    abase = x  + (size_t)(rt * 64) * INL;
    const ushort_t* bbase = wt + (size_t)(ct * 128 + br) * INL + bco;

    floatx4 comb[2][4];
    for (int mt = 0; mt < 2; ++mt)
        for (int nt = 0; nt < 4; ++nt)
            comb[mt][nt] = (floatx4){0.f, 0.f, 0.f, 0.f};

    float4 paf[4];
    uint4  pb[4];

    // prefetch (e=0, kc=0)
    {
        const float* p = abase + (size_t)arow * INL + acseg;
        paf[0] = *(const float4*)p;              paf[1] = *(const float4*)(p + 4);
        paf[2] = *(const float4*)(p + 32 * INL); paf[3] = *(const float4*)(p + 32 * INL + 4);
    }
    for (int i = 0; i < 4; ++i) pb[i] = *(const uint4*)(bbase + i * 8);

    for (int e = 0; e < NE; ++e) {
        for (int kc = 0; kc < 8; ++kc) {
            __syncthreads();   // prev tile's frag reads done; first iter: wTab ready
            // store staged tile: A scaled by combine weight, converted to bf16
            {
                float wa = wTab[arow * NE + e];
                float wb = wTab[(arow + 32) * NE + e];
                uint4 w0, w1;
                w0.x = pkbf(paf[0].x * wa, paf[0].y * wa);
                w0.y = pkbf(paf[0].z * wa, paf[0].w * wa);
                w0.z = pkbf(paf[1].x * wa, paf[1].y * wa);
                w0.w = pkbf(paf[1].z * wa, paf[1].w * wa);
                w1.x = pkbf(paf[2].x * wb, paf[2].y * wb);
                w1.y = pkbf(paf[2].z * wb, paf[2].w * wb);
                w1.z = pkbf(paf[3].x * wb, paf[3].y * wb);
                w1.w = pkbf(paf[3].z * wb, paf[3].w * wb);
                *(uint4*)&Alds[arow * LDP + acseg] = w0;
                *(uint4*)&Alds[(arow + 32) * LDP + acseg] = w1;
            }
            *(uint4*)&Blds[br * LDP + bco]      = pb[0];
            *(uint4*)&Blds[br * LDP + bco + 8]  = pb[1];
            *(uint4*)&Blds[br * LDP + bco + 16] = pb[2];
            *(uint4*)&Blds[br * LDP + bco + 24] = pb[3];
            __syncthreads();

            // prefetch next tile (flies during MFMA)
            int ne = e, nkc = kc + 1;
            if (nkc == 8) { nkc = 0; ne = e + 1; }
            if (ne < NE) {
                const float* p = abase + (size_t)arow * INL + nkc * 64 + acseg;
                paf[0] = *(const float4*)p;              paf[1] = *(const float4*)(p + 4);
                paf[2] = *(const float4*)(p + 32 * INL); paf[3] = *(const float4*)(p + 32 * INL + 4);
                const ushort_t* bsrc = bbase + (size_t)ne * OUTL * INL + nkc * 64;
                for (int i = 0; i < 4; ++i) pb[i] = *(const uint4*)(bsrc + i * 8);
            }

            // compute tile
            for (int ks = 0; ks < 64; ks += 32) {
                short8 af[2], bf[4];
                for (int mt = 0; mt < 2; ++mt)
                    af[mt] = *(const short8*)&Alds[(wm + mt * 16 + mrow) * LDP + ks + q8];
                for (int nt = 0; nt < 4; ++nt)
                    bf[nt] = *(const short8*)&Blds[(wn + nt * 16 + mrow) * LDP + ks + q8];
                for (int mt = 0; mt < 2; ++mt)
                    for (int nt = 0; nt < 4; ++nt)
                        comb[mt][nt] = __builtin_amdgcn_mfma_f32_16x16x32_bf16(
                            af[mt], bf[nt], comb[mt][nt], 0, 0, 0);
            }
        }
    }

    // epilogue: out = comb + rw0*bet_eff[e0] + rw1*bet_eff[e1], single plain store
    for (int mt = 0; mt < 2; ++mt) {
        for (int ri = 0; ri < 4; ++ri) {
            int row = wm + mt * 16 + qr + ri;
            int tok = rt * 64 + row;
            int es = eTab[row];
            int e0 = es & 255, e1 = es >> 8;
            float2 rv = rTab[row];
            for (int nt = 0; nt < 4; ++nt) {
                int col = ct * 128 + wn + nt * 16 + (lane & 15);
                float bet = rv.x * wsBet[e0 * OUTL + col] + rv.y * wsBet[e1 * OUTL + col];
                out[(size_t)tok * OUTL + col] = comb[mt][nt][ri] + bet;
            }
        }
    }
}

extern "C" void kernel_launch(void* const* d_in, const int* in_sizes, int n_in,
                              void* d_out, int out_size, void* d_ws, size_t ws_size,
                              hipStream_t stream) {
    const float* x        = (const float*)d_in[0];
    const float* ins      = (const float*)d_in[1];
    const float* gate_w   = (const float*)d_in[2];
    const float* expert_w = (const float*)d_in[3];
    const float* expert_b = (const float*)d_in[4];
    const float* gamma_w  = (const float*)d_in[5];
    const float* beta_w   = (const float*)d_in[6];
    const float* rmod_w   = (const float*)d_in[7];
    float* out = (float*)d_out;

    char* ws = (char*)d_ws;
    float*    wsS    = (float*)(ws + WS_S);
    float*    wsGam  = (float*)(ws + WS_GAM);
    float*    wsRgam = (float*)(ws + WS_RGAM);
    float*    wsBet  = (float*)(ws + WS_BET);
    int*      selE   = (int*)(ws + WS_SELE);
    float4*   selW   = (float4*)(ws + WS_SELW);
    ushort_t* wt     = (ushort_t*)(ws + WS_WT);

    // independent: W transpose+convert
    k_wt<<<dim3(8, 8, 8), 256, 0, stream>>>(expert_w, wt);
    // stats -> bet -> route -> gemm (stream-ordered dependencies)
    k_stats<<<1, 256, 0, stream>>>(ins, gamma_w, rmod_w, wsS, wsGam, wsRgam);
    k_bet<<<dim3(16, 8), 256, 0, stream>>>(beta_w, expert_b, wsS, wsGam, wsBet);
    k_route<<<N_TOK / 4, 256, 0, stream>>>(x, gate_w, wsGam, wsRgam, selE, selW);
    k_gemm<<<512, 256, 0, stream>>>(x, wt, selE, selW, wsBet, out);
}

// Round 6
// 270.141 us; speedup vs baseline: 1.2662x; 1.1475x over previous
//
#include <hip/hip_runtime.h>
#include <hip/hip_bf16.h>

// Problem constants
#define N_TOK 8192
#define INL   512
#define OUTL  512
#define NE    8
#define NI    16

typedef unsigned short ushort_t;
typedef unsigned int   uint_t;
typedef short  short8  __attribute__((ext_vector_type(8)));
typedef float  floatx4 __attribute__((ext_vector_type(4)));

// ---------------- workspace layout (bytes), ends 4376640 (<4.59MB known-safe) ----
#define WS_S      0u         // float[512]
#define WS_GAM    2048u      // float[8]
#define WS_RGAM   2080u      // float[8]
#define WS_BET    2112u      // float[4096]   : bet_eff[e][d] = bet + gam*b
#define WS_SELE   18496u     // int[8192]     : e0 | e1<<8
#define WS_SELW   51264u     // float4[8192]  : {rw0*gam0, rw1*gam1, rw0, rw1}
#define WS_WT     182336u    // ushort[8*512*512] : W^T bf16 [e][d][l]

__device__ __forceinline__ ushort_t f2bf(float f) {
    uint_t b = __float_as_uint(f);
    return (ushort_t)((b + 0x7FFFu + ((b >> 16) & 1u)) >> 16);   // RNE
}
__device__ __forceinline__ uint_t pkbf(float a, float b) {
    __hip_bfloat162 h = __float22bfloat162_rn(make_float2(a, b));  // v_cvt_pk_bf16_f32
    union { __hip_bfloat162 h2; uint_t u; } cv;
    cv.h2 = h;
    return cv.u;
}

// ---------------- K1: s[h], gam[e], rgam[e] (for router) ----------------
__global__ void k_stats(const float* __restrict__ ins,
                        const float* __restrict__ gamma_w,
                        const float* __restrict__ rmod_w,
                        float* __restrict__ wsS, float* __restrict__ wsGam,
                        float* __restrict__ wsRgam) {
    __shared__ float sS[INL];
    __shared__ float pg[64], pr[64];
    int tid = threadIdx.x;
    for (int h = tid; h < INL; h += 256) {
        float a = 0.f;
        for (int n = 0; n < NI; ++n) a += ins[n * INL + h];
        sS[h] = a;
        wsS[h] = a;
    }
    __syncthreads();
    if (tid < 64) {
        int e = tid & 7, qq = tid >> 3;
        float g = 0.f, r = 0.f;
        for (int j = 0; j < 64; ++j) {
            int h = qq * 64 + j;
            float sv = sS[h];
            g += sv * gamma_w[e * INL + h];
            r += sv * rmod_w[h * NE + e];
        }
        pg[tid] = g; pr[tid] = r;
    }
    __syncthreads();
    if (tid < NE) {
        float g = 0.f, r = 0.f;
        for (int qq = 0; qq < 8; ++qq) { g += pg[qq * 8 + tid]; r += pr[qq * 8 + tid]; }
        wsGam[tid]  = g * (1.f / NI);
        wsRgam[tid] = r * (1.f / NI);
    }
}

// ---------------- K2: bet_eff[e][d] — self-contained (computes own s, gam) --------
__global__ void k_bet(const float* __restrict__ ins,
                      const float* __restrict__ gamma_w,
                      const float* __restrict__ beta_w,
                      const float* __restrict__ expert_b,
                      float* __restrict__ wsBet) {
    __shared__ float sS[INL];
    __shared__ float red[256];
    __shared__ float gamS;
    int e = blockIdx.y;
    int dBase = blockIdx.x * 32;
    int tid = threadIdx.x;
    for (int h = tid; h < INL; h += 256) {
        float a = 0.f;
        for (int n = 0; n < NI; ++n) a += ins[n * INL + h];
        sS[h] = a;
    }
    __syncthreads();
    // gam_e = dot(s, gamma_w[e]) / NI  (64-lane partial + serial finish)
    if (tid < 64) {
        float g = 0.f;
        for (int j = 0; j < 8; ++j) g += sS[tid * 8 + j] * gamma_w[e * INL + tid * 8 + j];
        for (int off = 32; off >= 1; off >>= 1) g += __shfl_xor(g, off, 64);
        if (tid == 0) gamS = g * (1.f / NI);
    }
    int doff = tid & 31, hq = tid >> 5;
    float a = 0.f;
    for (int j = 0; j < 64; ++j) {
        int h = hq * 64 + j;
        a += sS[h] * beta_w[(e * INL + h) * OUTL + dBase + doff];
    }
    red[tid] = a;
    __syncthreads();
    if (tid < 32) {
        float t = 0.f;
        for (int k = 0; k < 8; ++k) t += red[k * 32 + tid];
        int d = dBase + tid;
        wsBet[e * OUTL + d] = t * (1.f / NI) + gamS * expert_b[e * OUTL + d];
    }
}

// ---------------- K3: router (fp32 logits), 16 tokens/block ----------------
__global__ void k_route(const float* __restrict__ x,
                        const float* __restrict__ gate_w,
                        const float* __restrict__ wsGam,
                        const float* __restrict__ wsRgam,
                        int* __restrict__ selE, float4* __restrict__ selW) {
    __shared__ float gateT[NE * INL];   // 16 KB, [e][l]
    int tid = threadIdx.x;
    for (int i = 0; i < 16; ++i) {
        int f = tid + 256 * i;
        float v = gate_w[f];
        gateT[(f & 7) * INL + (f >> 3)] = v;
    }
    __syncthreads();

    int w = tid >> 6, lane = tid & 63;
    int tbase = blockIdx.x * 16 + w * 4;

    for (int tt = 0; tt < 4; ++tt) {
        int t = tbase + tt;
        float2 xv[4];
        for (int i = 0; i < 4; ++i)
            xv[i] = *(const float2*)(x + (size_t)t * INL + 2 * lane + 128 * i);

        float acc[NE];
        for (int e = 0; e < NE; ++e) acc[e] = 0.f;
        for (int i = 0; i < 4; ++i) {
            int c = 2 * lane + 128 * i;
            for (int e = 0; e < NE; ++e)
                acc[e] += xv[i].x * gateT[e * INL + c] + xv[i].y * gateT[e * INL + c + 1];
        }
        for (int e = 0; e < NE; ++e) {
            float a = acc[e];
            for (int off = 32; off >= 1; off >>= 1) a += __shfl_xor(a, off, 64);
            acc[e] = a;
        }
        float logit[NE];
        for (int e = 0; e < NE; ++e) logit[e] = acc[e] + wsRgam[e];

        int i0 = 0; float m0 = logit[0];
        for (int e = 1; e < NE; ++e) if (logit[e] > m0) { m0 = logit[e]; i0 = e; }
        int i1 = -1; float m1 = -3.4e38f;
        for (int e = 0; e < NE; ++e) if (e != i0 && logit[e] > m1) { m1 = logit[e]; i1 = e; }

        float S = 0.f;
        for (int e = 0; e < NE; ++e) S += expf(logit[e] - m0);
        float rw0 = 1.0f / S;
        float rw1 = expf(m1 - m0) / S;

        if (lane == 0) {
            selE[t] = i0 | (i1 << 8);
            selW[t] = make_float4(rw0 * wsGam[i0], rw1 * wsGam[i1], rw0, rw1);
        }
    }
}

// ---------------- K4: W [e][l][d] fp32 -> Wt [e][d][l] bf16 ----------------
__global__ void k_wt(const float* __restrict__ expert_w, ushort_t* __restrict__ wt) {
    __shared__ float tile[64][65];
    int e = blockIdx.z;
    int lt = blockIdx.y * 64, dt = blockIdx.x * 64;
    int tid = threadIdx.x;
    int dIdx = tid & 63, lq = tid >> 6;
    for (int i = 0; i < 16; ++i) {
        int l = lq * 16 + i;
        tile[l][dIdx] = expert_w[(e * INL + lt + l) * OUTL + dt + dIdx];
    }
    __syncthreads();
    int lIdx = tid & 63, dq = tid >> 6;
    for (int i = 0; i < 16; ++i) {
        int d = dq * 16 + i;
        wt[(e * OUTL + dt + d) * INL + lt + lIdx] = f2bf(tile[lIdx][d]);
    }
}

// ---------------- K5: dense all-expert GEMM ----------------
// M=64 x N=128 block. kc outer (A fragment rows held in registers, loaded ONCE
// per kc), e inner (A rescaled per expert in VALU; MFMA accumulation is
// order-free so a single comb accumulator integrates all experts).
// B double-buffered in LDS -> ONE barrier per (kc,e) iteration.
#define LDP 72   // LDS pitch in bf16 elems
__global__ __launch_bounds__(256, 3)
void k_gemm(const float* __restrict__ x, const ushort_t* __restrict__ wt,
            const int* __restrict__ selE, const float4* __restrict__ selW,
            const float* __restrict__ wsBet, float* __restrict__ out) {
    int bx = blockIdx.x;
    int rt = bx & 127;                 // token slab: rows rt*64..+64
    int ct = bx >> 7;                  // col slab: ct*128..+128
    __shared__ ushort_t Blds[2][128 * LDP];   // 2 x 18 KB

    int tid = threadIdx.x;
    int wid = tid >> 6, lane = tid & 63;
    int wm = (wid >> 1) * 32, wn = (wid & 1) * 64;
    int mrow = lane & 15, q8 = (lane >> 4) * 8, qr = (lane >> 4) * 4;

    // per-lane combine weights for the 2 A-fragment rows this lane feeds
    float wv[2][NE];
    for (int mt = 0; mt < 2; ++mt) {
        int tok = rt * 64 + wm + mt * 16 + mrow;
        int es = selE[tok];
        float4 w4 = selW[tok];
        int e0 = es & 255, e1 = es >> 8;
        for (int e = 0; e < NE; ++e)
            wv[mt][e] = (e == e0) ? w4.x : ((e == e1) ? w4.y : 0.f);
    }

    // B staging map: row br (0..127), 32 bf16 starting at bco
    int br = tid >> 1, bco = (tid & 1) * 32;
    const ushort_t* bbase = wt + (size_t)(ct * 128 + br) * INL + bco;

    // A fragment row pointers (8 contiguous fp32 per (mt,ks) per kc)
    const float* arow[2];
    for (int mt = 0; mt < 2; ++mt)
        arow[mt] = x + (size_t)(rt * 64 + wm + mt * 16 + mrow) * INL + q8;

    floatx4 comb[2][4];
    for (int mt = 0; mt < 2; ++mt)
        for (int nt = 0; nt < 4; ++nt)
            comb[mt][nt] = (floatx4){0.f, 0.f, 0.f, 0.f};

    uint4 pb[4];
    for (int i = 0; i < 4; ++i) pb[i] = *(const uint4*)(bbase + i * 8);   // (kc=0,e=0)

    float4 ar[2][2][2];   // [mt][ksIdx][half] raw fp32 A fragments for current kc

    for (int kc = 0; kc < 8; ++kc) {
        // load A fragments for this kc (once; reused across all 8 experts)
        for (int mt = 0; mt < 2; ++mt)
            for (int ks = 0; ks < 2; ++ks) {
                const float* p = arow[mt] + kc * 64 + ks * 32;
                ar[mt][ks][0] = *(const float4*)p;
                ar[mt][ks][1] = *(const float4*)(p + 4);
            }

        for (int e = 0; e < NE; ++e) {
            int it = kc * 8 + e;
            int buf = it & 1;
            // stage prefetched B into LDS buffer
            *(uint4*)&Blds[buf][br * LDP + bco]      = pb[0];
            *(uint4*)&Blds[buf][br * LDP + bco + 8]  = pb[1];
            *(uint4*)&Blds[buf][br * LDP + bco + 16] = pb[2];
            *(uint4*)&Blds[buf][br * LDP + bco + 24] = pb[3];
            // prefetch next (kc,e) B tile
            int ne = e + 1, nkc = kc;
            if (ne == NE) { ne = 0; nkc = kc + 1; }
            if (nkc < 8) {
                const ushort_t* bsrc = bbase + (size_t)ne * OUTL * INL + nkc * 64;
                for (int i = 0; i < 4; ++i) pb[i] = *(const uint4*)(bsrc + i * 8);
            }
            __syncthreads();   // buf visible; prev buf's reads (prog-order earlier) done

            // compute: A fragments rescaled from registers, B from LDS
            for (int ks = 0; ks < 2; ++ks) {
                short8 bf[4];
                for (int nt = 0; nt < 4; ++nt)
                    bf[nt] = *(const short8*)&Blds[buf][(wn + nt * 16 + mrow) * LDP + ks * 32 + q8];
                for (int mt = 0; mt < 2; ++mt) {
                    float w = wv[mt][e];
                    union { uint4 u; short8 s; } af;
                    float4 a0 = ar[mt][ks][0], a1 = ar[mt][ks][1];
                    af.u.x = pkbf(a0.x * w, a0.y * w);
                    af.u.y = pkbf(a0.z * w, a0.w * w);
                    af.u.z = pkbf(a1.x * w, a1.y * w);
                    af.u.w = pkbf(a1.z * w, a1.w * w);
                    for (int nt = 0; nt < 4; ++nt)
                        comb[mt][nt] = __builtin_amdgcn_mfma_f32_16x16x32_bf16(
                            af.s, bf[nt], comb[mt][nt], 0, 0, 0);
                }
            }
        }
    }

    // epilogue: out = comb + rw0*bet_eff[e0] + rw1*bet_eff[e1], single plain store
    for (int mt = 0; mt < 2; ++mt) {
        for (int ri = 0; ri < 4; ++ri) {
            int row = wm + mt * 16 + qr + ri;
            int tok = rt * 64 + row;
            int es = selE[tok];
            float4 w4 = selW[tok];
            int e0 = es & 255, e1 = es >> 8;
            for (int nt = 0; nt < 4; ++nt) {
                int col = ct * 128 + wn + nt * 16 + (lane & 15);
                float bet = w4.z * wsBet[e0 * OUTL + col] + w4.w * wsBet[e1 * OUTL + col];
                out[(size_t)tok * OUTL + col] = comb[mt][nt][ri] + bet;
            }
        }
    }
}

extern "C" void kernel_launch(void* const* d_in, const int* in_sizes, int n_in,
                              void* d_out, int out_size, void* d_ws, size_t ws_size,
                              hipStream_t stream) {
    const float* x        = (const float*)d_in[0];
    const float* ins      = (const float*)d_in[1];
    const float* gate_w   = (const float*)d_in[2];
    const float* expert_w = (const float*)d_in[3];
    const float* expert_b = (const float*)d_in[4];
    const float* gamma_w  = (const float*)d_in[5];
    const float* beta_w   = (const float*)d_in[6];
    const float* rmod_w   = (const float*)d_in[7];
    float* out = (float*)d_out;

    char* ws = (char*)d_ws;
    float*    wsS    = (float*)(ws + WS_S);
    float*    wsGam  = (float*)(ws + WS_GAM);
    float*    wsRgam = (float*)(ws + WS_RGAM);
    float*    wsBet  = (float*)(ws + WS_BET);
    int*      selE   = (int*)(ws + WS_SELE);
    float4*   selW   = (float4*)(ws + WS_SELW);
    ushort_t* wt     = (ushort_t*)(ws + WS_WT);

    // k_stats first (tiny; k_route depends on it). k_wt / k_bet independent.
    k_stats<<<1, 256, 0, stream>>>(ins, gamma_w, rmod_w, wsS, wsGam, wsRgam);
    k_wt<<<dim3(8, 8, 8), 256, 0, stream>>>(expert_w, wt);
    k_bet<<<dim3(16, 8), 256, 0, stream>>>(ins, gamma_w, beta_w, expert_b, wsBet);
    k_route<<<N_TOK / 16, 256, 0, stream>>>(x, gate_w, wsGam, wsRgam, selE, selW);
    k_gemm<<<512, 256, 0, stream>>>(x, wt, selE, selW, wsBet, out);
}

// Round 7
// 237.378 us; speedup vs baseline: 1.4410x; 1.1380x over previous
//
#include <hip/hip_runtime.h>
#include <hip/hip_bf16.h>

// Problem constants
#define N_TOK 8192
#define INL   512
#define OUTL  512
#define NE    8
#define NI    16

typedef unsigned short ushort_t;
typedef unsigned int   uint_t;
typedef short  short8  __attribute__((ext_vector_type(8)));
typedef float  floatx4 __attribute__((ext_vector_type(4)));

// ---------------- workspace layout (bytes), ends 4376640 ----
#define WS_S      0u         // float[512]
#define WS_GAM    2048u      // float[8]
#define WS_RGAM   2080u      // float[8]
#define WS_BET    2112u      // float[4096]   : bet_eff[e][d] = bet + gam*b
#define WS_SELE   18496u     // int[8192]     : e0 | e1<<8
#define WS_SELW   51264u     // float4[8192]  : {rw0*gam0, rw1*gam1, rw0, rw1}
#define WS_WT     182336u    // ushort[8*512*512] : W^T bf16 [e][d][l]

__device__ __forceinline__ ushort_t f2bf(float f) {
    uint_t b = __float_as_uint(f);
    return (ushort_t)((b + 0x7FFFu + ((b >> 16) & 1u)) >> 16);   // RNE
}
__device__ __forceinline__ uint_t pkbf(float a, float b) {
    __hip_bfloat162 h = __float22bfloat162_rn(make_float2(a, b));  // v_cvt_pk_bf16_f32
    union { __hip_bfloat162 h2; uint_t u; } cv;
    cv.h2 = h;
    return cv.u;
}

// ---------------- K1: s[h], gam[e], rgam[e] (for router) ----------------
__global__ void k_stats(const float* __restrict__ ins,
                        const float* __restrict__ gamma_w,
                        const float* __restrict__ rmod_w,
                        float* __restrict__ wsS, float* __restrict__ wsGam,
                        float* __restrict__ wsRgam) {
    __shared__ float sS[INL];
    __shared__ float pg[64], pr[64];
    int tid = threadIdx.x;
    for (int h = tid; h < INL; h += 256) {
        float a = 0.f;
        for (int n = 0; n < NI; ++n) a += ins[n * INL + h];
        sS[h] = a;
        wsS[h] = a;
    }
    __syncthreads();
    if (tid < 64) {
        int e = tid & 7, qq = tid >> 3;
        float g = 0.f, r = 0.f;
        for (int j = 0; j < 64; ++j) {
            int h = qq * 64 + j;
            float sv = sS[h];
            g += sv * gamma_w[e * INL + h];
            r += sv * rmod_w[h * NE + e];
        }
        pg[tid] = g; pr[tid] = r;
    }
    __syncthreads();
    if (tid < NE) {
        float g = 0.f, r = 0.f;
        for (int qq = 0; qq < 8; ++qq) { g += pg[qq * 8 + tid]; r += pr[qq * 8 + tid]; }
        wsGam[tid]  = g * (1.f / NI);
        wsRgam[tid] = r * (1.f / NI);
    }
}

// ---------------- K2: bet_eff[e][d] — self-contained ----------------
__global__ void k_bet(const float* __restrict__ ins,
                      const float* __restrict__ gamma_w,
                      const float* __restrict__ beta_w,
                      const float* __restrict__ expert_b,
                      float* __restrict__ wsBet) {
    __shared__ float sS[INL];
    __shared__ float red[256];
    __shared__ float gamS;
    int e = blockIdx.y;
    int dBase = blockIdx.x * 32;
    int tid = threadIdx.x;
    for (int h = tid; h < INL; h += 256) {
        float a = 0.f;
        for (int n = 0; n < NI; ++n) a += ins[n * INL + h];
        sS[h] = a;
    }
    __syncthreads();
    if (tid < 64) {
        float g = 0.f;
        for (int j = 0; j < 8; ++j) g += sS[tid * 8 + j] * gamma_w[e * INL + tid * 8 + j];
        for (int off = 32; off >= 1; off >>= 1) g += __shfl_xor(g, off, 64);
        if (tid == 0) gamS = g * (1.f / NI);
    }
    int doff = tid & 31, hq = tid >> 5;
    float a = 0.f;
    for (int j = 0; j < 64; ++j) {
        int h = hq * 64 + j;
        a += sS[h] * beta_w[(e * INL + h) * OUTL + dBase + doff];
    }
    red[tid] = a;
    __syncthreads();
    if (tid < 32) {
        float t = 0.f;
        for (int k = 0; k < 8; ++k) t += red[k * 32 + tid];
        int d = dBase + tid;
        wsBet[e * OUTL + d] = t * (1.f / NI) + gamS * expert_b[e * OUTL + d];
    }
}

// ---------------- K3: router (fp32 logits), 16 tokens/block ----------------
__global__ void k_route(const float* __restrict__ x,
                        const float* __restrict__ gate_w,
                        const float* __restrict__ wsGam,
                        const float* __restrict__ wsRgam,
                        int* __restrict__ selE, float4* __restrict__ selW) {
    __shared__ float gateT[NE * INL];   // 16 KB, [e][l]
    int tid = threadIdx.x;
    for (int i = 0; i < 16; ++i) {
        int f = tid + 256 * i;
        float v = gate_w[f];
        gateT[(f & 7) * INL + (f >> 3)] = v;
    }
    __syncthreads();

    int w = tid >> 6, lane = tid & 63;
    int tbase = blockIdx.x * 16 + w * 4;

    for (int tt = 0; tt < 4; ++tt) {
        int t = tbase + tt;
        float2 xv[4];
        for (int i = 0; i < 4; ++i)
            xv[i] = *(const float2*)(x + (size_t)t * INL + 2 * lane + 128 * i);

        float acc[NE];
        for (int e = 0; e < NE; ++e) acc[e] = 0.f;
        for (int i = 0; i < 4; ++i) {
            int c = 2 * lane + 128 * i;
            for (int e = 0; e < NE; ++e)
                acc[e] += xv[i].x * gateT[e * INL + c] + xv[i].y * gateT[e * INL + c + 1];
        }
        for (int e = 0; e < NE; ++e) {
            float a = acc[e];
            for (int off = 32; off >= 1; off >>= 1) a += __shfl_xor(a, off, 64);
            acc[e] = a;
        }
        float logit[NE];
        for (int e = 0; e < NE; ++e) logit[e] = acc[e] + wsRgam[e];

        int i0 = 0; float m0 = logit[0];
        for (int e = 1; e < NE; ++e) if (logit[e] > m0) { m0 = logit[e]; i0 = e; }
        int i1 = -1; float m1 = -3.4e38f;
        for (int e = 0; e < NE; ++e) if (e != i0 && logit[e] > m1) { m1 = logit[e]; i1 = e; }

        float S = 0.f;
        for (int e = 0; e < NE; ++e) S += expf(logit[e] - m0);
        float rw0 = 1.0f / S;
        float rw1 = expf(m1 - m0) / S;

        if (lane == 0) {
            selE[t] = i0 | (i1 << 8);
            selW[t] = make_float4(rw0 * wsGam[i0], rw1 * wsGam[i1], rw0, rw1);
        }
    }
}

// ---------------- K4: W [e][l][d] fp32 -> Wt [e][d][l] bf16 ----------------
__global__ void k_wt(const float* __restrict__ expert_w, ushort_t* __restrict__ wt) {
    __shared__ float tile[64][65];
    int e = blockIdx.z;
    int lt = blockIdx.y * 64, dt = blockIdx.x * 64;
    int tid = threadIdx.x;
    int dIdx = tid & 63, lq = tid >> 6;
    for (int i = 0; i < 16; ++i) {
        int l = lq * 16 + i;
        tile[l][dIdx] = expert_w[(e * INL + lt + l) * OUTL + dt + dIdx];
    }
    __syncthreads();
    int lIdx = tid & 63, dq = tid >> 6;
    for (int i = 0; i < 16; ++i) {
        int d = dq * 16 + i;
        wt[(e * OUTL + dt + d) * INL + lt + lIdx] = f2bf(tile[lIdx][d]);
    }
}

// ---------------- K5: dense all-expert GEMM — NO LDS, NO BARRIERS ----------------
// Block = 4 waves; wave w computes rows (rt*128 + w*32 .. +32) x cols (ct*64..+64).
// B fragments loaded per-lane DIRECTLY from wt (8 contiguous bf16 along k =
// one global_load_dwordx4); register-prefetched one step ahead. A fragments
// register-prefetched one kc ahead; rescaled per expert in VALU; single comb
// accumulator integrates all 8 experts. Waves run free — latency hidden by
// compiler vmcnt scheduling + 8 waves/CU, not barriers.
__global__ __launch_bounds__(256, 2)
void k_gemm(const float* __restrict__ x, const ushort_t* __restrict__ wt,
            const int* __restrict__ selE, const float4* __restrict__ selW,
            const float* __restrict__ wsBet, float* __restrict__ out) {
    int bx = blockIdx.x;
    int rt = bx & 63;                  // token slab: rows rt*128..+128
    int ct = bx >> 6;                  // col slab: ct*64..+64
    int tid = threadIdx.x;
    int wid = tid >> 6, lane = tid & 63;
    int wm = wid * 32;                 // wave's row offset within the 128-slab
    int mrow = lane & 15, q8 = (lane >> 4) * 8, qr = (lane >> 4) * 4;

    // per-lane combine weights for this lane's 2 A rows
    float wv[2][NE];
    for (int mt = 0; mt < 2; ++mt) {
        int tok = rt * 128 + wm + mt * 16 + mrow;
        int es = selE[tok];
        float4 w4 = selW[tok];
        int e0 = es & 255, e1 = es >> 8;
        for (int e = 0; e < NE; ++e)
            wv[mt][e] = (e == e0) ? w4.x : ((e == e1) ? w4.y : 0.f);
    }

    // A row pointers (8 contiguous fp32 at k-offset q8)
    const float* arow[2];
    for (int mt = 0; mt < 2; ++mt)
        arow[mt] = x + (size_t)(rt * 128 + wm + mt * 16 + mrow) * INL + q8;
    // B row pointers: col = ct*64 + nt*16 + mrow, k-offset q8
    const ushort_t* brow[4];
    for (int nt = 0; nt < 4; ++nt)
        brow[nt] = wt + (size_t)(ct * 64 + nt * 16 + mrow) * INL + q8;

    floatx4 comb[2][4];
    for (int mt = 0; mt < 2; ++mt)
        for (int nt = 0; nt < 4; ++nt)
            comb[mt][nt] = (floatx4){0.f, 0.f, 0.f, 0.f};

    // prefetch A (kc=0) and B (kc=0,e=0,ks=0)
    float4 arn[2][2][2];
    for (int mt = 0; mt < 2; ++mt)
        for (int ks = 0; ks < 2; ++ks) {
            arn[mt][ks][0] = *(const float4*)(arow[mt] + ks * 32);
            arn[mt][ks][1] = *(const float4*)(arow[mt] + ks * 32 + 4);
        }
    uint4 pb[4];
    for (int nt = 0; nt < 4; ++nt) pb[nt] = *(const uint4*)(brow[nt]);

    #pragma unroll 1
    for (int kc = 0; kc < 8; ++kc) {
        // current A fragments; start prefetching kc+1 (flies during the e-loop)
        float4 ar[2][2][2];
        for (int mt = 0; mt < 2; ++mt)
            for (int ks = 0; ks < 2; ++ks)
                for (int h = 0; h < 2; ++h) ar[mt][ks][h] = arn[mt][ks][h];
        if (kc < 7) {
            for (int mt = 0; mt < 2; ++mt)
                for (int ks = 0; ks < 2; ++ks) {
                    const float* p = arow[mt] + (kc + 1) * 64 + ks * 32;
                    arn[mt][ks][0] = *(const float4*)p;
                    arn[mt][ks][1] = *(const float4*)(p + 4);
                }
        }

        #pragma unroll
        for (int e = 0; e < NE; ++e) {
            #pragma unroll
            for (int ks = 0; ks < 2; ++ks) {
                // take current B frags; prefetch next step's
                uint4 cb[4];
                for (int nt = 0; nt < 4; ++nt) cb[nt] = pb[nt];
                if (!(e == NE - 1 && ks == 1)) {
                    int ne = (ks == 1) ? e + 1 : e;
                    int nks = (ks == 1) ? 0 : 1;
                    size_t boff = (size_t)ne * (OUTL * INL) + (size_t)kc * 64 + nks * 32;
                    for (int nt = 0; nt < 4; ++nt)
                        pb[nt] = *(const uint4*)(brow[nt] + boff);
                } else if (kc < 7) {
                    size_t boff = (size_t)(kc + 1) * 64;   // e=0, ks=0 of next kc
                    for (int nt = 0; nt < 4; ++nt)
                        pb[nt] = *(const uint4*)(brow[nt] + boff);
                }
                // pack A (scaled) and MFMA
                for (int mt = 0; mt < 2; ++mt) {
                    float w = wv[mt][e];
                    union { uint4 u; short8 s; } af;
                    float4 a0 = ar[mt][ks][0], a1 = ar[mt][ks][1];
                    af.u.x = pkbf(a0.x * w, a0.y * w);
                    af.u.y = pkbf(a0.z * w, a0.w * w);
                    af.u.z = pkbf(a1.x * w, a1.y * w);
                    af.u.w = pkbf(a1.z * w, a1.w * w);
                    union { uint4 u; short8 s; } bu0, bu1, bu2, bu3;
                    bu0.u = cb[0]; bu1.u = cb[1]; bu2.u = cb[2]; bu3.u = cb[3];
                    comb[mt][0] = __builtin_amdgcn_mfma_f32_16x16x32_bf16(af.s, bu0.s, comb[mt][0], 0, 0, 0);
                    comb[mt][1] = __builtin_amdgcn_mfma_f32_16x16x32_bf16(af.s, bu1.s, comb[mt][1], 0, 0, 0);
                    comb[mt][2] = __builtin_amdgcn_mfma_f32_16x16x32_bf16(af.s, bu2.s, comb[mt][2], 0, 0, 0);
                    comb[mt][3] = __builtin_amdgcn_mfma_f32_16x16x32_bf16(af.s, bu3.s, comb[mt][3], 0, 0, 0);
                }
            }
        }
    }

    // epilogue: out = comb + rw0*bet_eff[e0] + rw1*bet_eff[e1], single plain store
    for (int mt = 0; mt < 2; ++mt) {
        for (int ri = 0; ri < 4; ++ri) {
            int row = wm + mt * 16 + qr + ri;
            int tok = rt * 128 + row;
            int es = selE[tok];
            float4 w4 = selW[tok];
            int e0 = es & 255, e1 = es >> 8;
            for (int nt = 0; nt < 4; ++nt) {
                int col = ct * 64 + nt * 16 + (lane & 15);
                float bet = w4.z * wsBet[e0 * OUTL + col] + w4.w * wsBet[e1 * OUTL + col];
                out[(size_t)tok * OUTL + col] = comb[mt][nt][ri] + bet;
            }
        }
    }
}

extern "C" void kernel_launch(void* const* d_in, const int* in_sizes, int n_in,
                              void* d_out, int out_size, void* d_ws, size_t ws_size,
                              hipStream_t stream) {
    const float* x        = (const float*)d_in[0];
    const float* ins      = (const float*)d_in[1];
    const float* gate_w   = (const float*)d_in[2];
    const float* expert_w = (const float*)d_in[3];
    const float* expert_b = (const float*)d_in[4];
    const float* gamma_w  = (const float*)d_in[5];
    const float* beta_w   = (const float*)d_in[6];
    const float* rmod_w   = (const float*)d_in[7];
    float* out = (float*)d_out;

    char* ws = (char*)d_ws;
    float*    wsS    = (float*)(ws + WS_S);
    float*    wsGam  = (float*)(ws + WS_GAM);
    float*    wsRgam = (float*)(ws + WS_RGAM);
    float*    wsBet  = (float*)(ws + WS_BET);
    int*      selE   = (int*)(ws + WS_SELE);
    float4*   selW   = (float4*)(ws + WS_SELW);
    ushort_t* wt     = (ushort_t*)(ws + WS_WT);

    k_stats<<<1, 256, 0, stream>>>(ins, gamma_w, rmod_w, wsS, wsGam, wsRgam);
    k_wt<<<dim3(8, 8, 8), 256, 0, stream>>>(expert_w, wt);
    k_bet<<<dim3(16, 8), 256, 0, stream>>>(ins, gamma_w, beta_w, expert_b, wsBet);
    k_route<<<N_TOK / 16, 256, 0, stream>>>(x, gate_w, wsGam, wsRgam, selE, selW);
    k_gemm<<<512, 256, 0, stream>>>(x, wt, selE, selW, wsBet, out);
}

// Round 8
// 160.493 us; speedup vs baseline: 2.1313x; 1.4791x over previous
//
#include <hip/hip_runtime.h>
#include <hip/hip_bf16.h>

// Problem constants
#define N_TOK 8192
#define INL   512
#define OUTL  512
#define NE    8
#define NI    16

typedef unsigned short ushort_t;
typedef unsigned int   uint_t;
typedef short  short8  __attribute__((ext_vector_type(8)));
typedef float  floatx4 __attribute__((ext_vector_type(4)));

// ---------------- workspace layout (bytes), ends 4376640 ----
#define WS_S      0u         // float[512]
#define WS_GAM    2048u      // float[8]
#define WS_RGAM   2080u      // float[8]
#define WS_BET    2112u      // float[4096]   : bet_eff[e][d] = bet + gam*b
#define WS_SELE   18496u     // int[8192]     : e0 | e1<<8
#define WS_SELW   51264u     // float4[8192]  : {rw0*gam0, rw1*gam1, rw0, rw1}
#define WS_WT     182336u    // ushort[8*512*512] : W^T bf16 [e][d][l]

__device__ __forceinline__ ushort_t f2bf(float f) {
    uint_t b = __float_as_uint(f);
    return (ushort_t)((b + 0x7FFFu + ((b >> 16) & 1u)) >> 16);   // RNE
}
__device__ __forceinline__ uint_t pkbf(float a, float b) {
    __hip_bfloat162 h = __float22bfloat162_rn(make_float2(a, b));  // v_cvt_pk_bf16_f32
    union { __hip_bfloat162 h2; uint_t u; } cv;
    cv.h2 = h;
    return cv.u;
}
// async global->LDS DMA, 16 B per lane; LDS dest = wave-uniform base + lane*16
__device__ __forceinline__ void dma16(const ushort_t* g, ushort_t* l) {
    __builtin_amdgcn_global_load_lds(
        (const __attribute__((address_space(1))) void*)g,
        (__attribute__((address_space(3))) void*)l,
        16, 0, 0);
}

// ---------------- K1: s[h], gam[e], rgam[e] (for router) ----------------
__global__ void k_stats(const float* __restrict__ ins,
                        const float* __restrict__ gamma_w,
                        const float* __restrict__ rmod_w,
                        float* __restrict__ wsS, float* __restrict__ wsGam,
                        float* __restrict__ wsRgam) {
    __shared__ float sS[INL];
    __shared__ float pg[64], pr[64];
    int tid = threadIdx.x;
    for (int h = tid; h < INL; h += 256) {
        float a = 0.f;
        for (int n = 0; n < NI; ++n) a += ins[n * INL + h];
        sS[h] = a;
        wsS[h] = a;
    }
    __syncthreads();
    if (tid < 64) {
        int e = tid & 7, qq = tid >> 3;
        float g = 0.f, r = 0.f;
        for (int j = 0; j < 64; ++j) {
            int h = qq * 64 + j;
            float sv = sS[h];
            g += sv * gamma_w[e * INL + h];
            r += sv * rmod_w[h * NE + e];
        }
        pg[tid] = g; pr[tid] = r;
    }
    __syncthreads();
    if (tid < NE) {
        float g = 0.f, r = 0.f;
        for (int qq = 0; qq < 8; ++qq) { g += pg[qq * 8 + tid]; r += pr[qq * 8 + tid]; }
        wsGam[tid]  = g * (1.f / NI);
        wsRgam[tid] = r * (1.f / NI);
    }
}

// ---------------- K2: bet_eff[e][d] — self-contained ----------------
__global__ void k_bet(const float* __restrict__ ins,
                      const float* __restrict__ gamma_w,
                      const float* __restrict__ beta_w,
                      const float* __restrict__ expert_b,
                      float* __restrict__ wsBet) {
    __shared__ float sS[INL];
    __shared__ float red[256];
    __shared__ float gamS;
    int e = blockIdx.y;
    int dBase = blockIdx.x * 32;
    int tid = threadIdx.x;
    for (int h = tid; h < INL; h += 256) {
        float a = 0.f;
        for (int n = 0; n < NI; ++n) a += ins[n * INL + h];
        sS[h] = a;
    }
    __syncthreads();
    if (tid < 64) {
        float g = 0.f;
        for (int j = 0; j < 8; ++j) g += sS[tid * 8 + j] * gamma_w[e * INL + tid * 8 + j];
        for (int off = 32; off >= 1; off >>= 1) g += __shfl_xor(g, off, 64);
        if (tid == 0) gamS = g * (1.f / NI);
    }
    int doff = tid & 31, hq = tid >> 5;
    float a = 0.f;
    for (int j = 0; j < 64; ++j) {
        int h = hq * 64 + j;
        a += sS[h] * beta_w[(e * INL + h) * OUTL + dBase + doff];
    }
    red[tid] = a;
    __syncthreads();
    if (tid < 32) {
        float t = 0.f;
        for (int k = 0; k < 8; ++k) t += red[k * 32 + tid];
        int d = dBase + tid;
        wsBet[e * OUTL + d] = t * (1.f / NI) + gamS * expert_b[e * OUTL + d];
    }
}

// ---------------- K3: router (fp32 logits), 16 tokens/block ----------------
__global__ void k_route(const float* __restrict__ x,
                        const float* __restrict__ gate_w,
                        const float* __restrict__ wsGam,
                        const float* __restrict__ wsRgam,
                        int* __restrict__ selE, float4* __restrict__ selW) {
    __shared__ float gateT[NE * INL];   // 16 KB, [e][l]
    int tid = threadIdx.x;
    for (int i = 0; i < 16; ++i) {
        int f = tid + 256 * i;
        float v = gate_w[f];
        gateT[(f & 7) * INL + (f >> 3)] = v;
    }
    __syncthreads();

    int w = tid >> 6, lane = tid & 63;
    int tbase = blockIdx.x * 16 + w * 4;

    for (int tt = 0; tt < 4; ++tt) {
        int t = tbase + tt;
        float2 xv[4];
        for (int i = 0; i < 4; ++i)
            xv[i] = *(const float2*)(x + (size_t)t * INL + 2 * lane + 128 * i);

        float acc[NE];
        for (int e = 0; e < NE; ++e) acc[e] = 0.f;
        for (int i = 0; i < 4; ++i) {
            int c = 2 * lane + 128 * i;
            for (int e = 0; e < NE; ++e)
                acc[e] += xv[i].x * gateT[e * INL + c] + xv[i].y * gateT[e * INL + c + 1];
        }
        for (int e = 0; e < NE; ++e) {
            float a = acc[e];
            for (int off = 32; off >= 1; off >>= 1) a += __shfl_xor(a, off, 64);
            acc[e] = a;
        }
        float logit[NE];
        for (int e = 0; e < NE; ++e) logit[e] = acc[e] + wsRgam[e];

        int i0 = 0; float m0 = logit[0];
        for (int e = 1; e < NE; ++e) if (logit[e] > m0) { m0 = logit[e]; i0 = e; }
        int i1 = -1; float m1 = -3.4e38f;
        for (int e = 0; e < NE; ++e) if (e != i0 && logit[e] > m1) { m1 = logit[e]; i1 = e; }

        float S = 0.f;
        for (int e = 0; e < NE; ++e) S += expf(logit[e] - m0);
        float rw0 = 1.0f / S;
        float rw1 = expf(m1 - m0) / S;

        if (lane == 0) {
            selE[t] = i0 | (i1 << 8);
            selW[t] = make_float4(rw0 * wsGam[i0], rw1 * wsGam[i1], rw0, rw1);
        }
    }
}

// ---------------- K4: W [e][l][d] fp32 -> Wt [e][d][l] bf16 ----------------
__global__ void k_wt(const float* __restrict__ expert_w, ushort_t* __restrict__ wt) {
    __shared__ float tile[64][65];
    int e = blockIdx.z;
    int lt = blockIdx.y * 64, dt = blockIdx.x * 64;
    int tid = threadIdx.x;
    int dIdx = tid & 63, lq = tid >> 6;
    for (int i = 0; i < 16; ++i) {
        int l = lq * 16 + i;
        tile[l][dIdx] = expert_w[(e * INL + lt + l) * OUTL + dt + dIdx];
    }
    __syncthreads();
    int lIdx = tid & 63, dq = tid >> 6;
    for (int i = 0; i < 16; ++i) {
        int d = dq * 16 + i;
        wt[(e * OUTL + dt + d) * INL + lt + lIdx] = f2bf(tile[lIdx][d]);
    }
}

// ---------------- K5: dense all-expert GEMM — LDS-staged B via async DMA --------
// Block = M128 x N64, 4 waves (wave = 32 rows x 64 cols). Per (kc,e) step the
// 8 KB B tile is DMA'd to LDS (global_load_lds x2/thread), double-buffered:
//   issue DMA(next) -> compute(cur) -> __syncthreads  (drain overlaps compute)
// B traffic: once per block per step (vs per-wave in r7 => 4x less L2 load).
// LDS rotate swizzle: elem (col,k) at col*64 + ((k/8 + col)&7)*8 -> staging
// stays line-coalesced AND ds_read_b128 fragments are 2-way (free).
// A: per-lane fp32 registers, loaded once per kc, reused across 8 experts,
// scaled per expert (combine weight) + packed bf16 in VALU; single accumulator.
__global__ __launch_bounds__(256, 2)
void k_gemm(const float* __restrict__ x, const ushort_t* __restrict__ wt,
            const int* __restrict__ selE, const float4* __restrict__ selW,
            const float* __restrict__ wsBet, float* __restrict__ out) {
    int bx = blockIdx.x;
    int rt = bx & 63;                  // token slab: rows rt*128..+128
    int ct = bx >> 6;                  // col slab: ct*64..+64
    __shared__ ushort_t Blds[2][64 * 64];   // 2 x 8 KB, swizzled [col][k]

    int tid = threadIdx.x;
    int wid = tid >> 6, lane = tid & 63;
    int wm = wid * 32;
    int mrow = lane & 15, laneq = lane >> 4, q8 = laneq * 8, qr = laneq * 4;

    // per-lane combine weights for this lane's 2 A rows
    float wv[2][NE];
    for (int mt = 0; mt < 2; ++mt) {
        int tok = rt * 128 + wm + mt * 16 + mrow;
        int es = selE[tok];
        float4 w4 = selW[tok];
        int e0 = es & 255, e1 = es >> 8;
        for (int e = 0; e < NE; ++e)
            wv[mt][e] = (e == e0) ? w4.x : ((e == e1) ? w4.y : 0.f);
    }

    // A row pointers (8 contiguous fp32 at k-offset q8)
    const float* arow[2];
    for (int mt = 0; mt < 2; ++mt)
        arow[mt] = x + (size_t)(rt * 128 + wm + mt * 16 + mrow) * INL + q8;

    // B staging: thread stages chunks c0=tid, c1=tid+256 (chunk = 8 k-elems,16B)
    // chunk c -> col=c>>3, kslot=c&7, source kgrp=(kslot-col)&7
    int c0 = tid, c1 = tid + 256;
    int col0 = c0 >> 3, kg0 = ((c0 & 7) - col0) & 7;
    int col1 = c1 >> 3, kg1 = ((c1 & 7) - col1) & 7;
    const ushort_t* pB0 = wt + (size_t)(ct * 64 + col0) * INL + kg0 * 8;
    const ushort_t* pB1 = wt + (size_t)(ct * 64 + col1) * INL + kg1 * 8;
    ushort_t* ldsW0;   // wave-uniform LDS bases (lane*16B auto-added by HW)
    ushort_t* ldsW1;
    {
        int base0 = (wid * 64) * 8;          // chunk (0*256 + wid*64) * 8 elems
        int base1 = (256 + wid * 64) * 8;
        ldsW0 = &Blds[0][0] + base0;         // buf selected by adding 64*64*buf
        ldsW1 = &Blds[0][0] + base1;
    }

    // fragment read swizzle: col_l = nt*16+mrow ; rot(ks) = ((ks*4+laneq)+col_l)&7
    int fcol[4], frot0[4];
    for (int nt = 0; nt < 4; ++nt) {
        fcol[nt] = nt * 16 + mrow;
        frot0[nt] = (laneq + fcol[nt]) & 7;
    }

    floatx4 comb[2][4];
    for (int mt = 0; mt < 2; ++mt)
        for (int nt = 0; nt < 4; ++nt)
            comb[mt][nt] = (floatx4){0.f, 0.f, 0.f, 0.f};

    // prologue: DMA tile (kc=0,e=0) into buf0, drain
    dma16(pB0, ldsW0);
    dma16(pB1, ldsW1);
    __syncthreads();

    float4 ar[2][2][2];   // [mt][ks][half] fp32 A fragments for current kc

    #pragma unroll 1
    for (int kc = 0; kc < 8; ++kc) {
        // A fragments for this kc (reused across all 8 experts)
        for (int mt = 0; mt < 2; ++mt)
            for (int ks = 0; ks < 2; ++ks) {
                const float* p = arow[mt] + kc * 64 + ks * 32;
                ar[mt][ks][0] = *(const float4*)p;
                ar[mt][ks][1] = *(const float4*)(p + 4);
            }

        #pragma unroll
        for (int e = 0; e < NE; ++e) {
            int step = kc * 8 + e;
            int buf = step & 1;
            // issue DMA for next step into the other buffer (flies during compute)
            int ne = e + 1, nkc = kc;
            if (ne == NE) { ne = 0; nkc = kc + 1; }
            if (nkc < 8) {
                size_t off = (size_t)ne * (OUTL * INL) + (size_t)nkc * 64;
                int nb = (step + 1) & 1;
                dma16(pB0 + off, ldsW0 + nb * (64 * 64));
                dma16(pB1 + off, ldsW1 + nb * (64 * 64));
            }

            // compute current step from buf
            const ushort_t* B = &Blds[buf][0];
            short8 bf[4][2];
            for (int nt = 0; nt < 4; ++nt) {
                int cb = fcol[nt] * 64;
                bf[nt][0] = *(const short8*)&B[cb + frot0[nt] * 8];
                bf[nt][1] = *(const short8*)&B[cb + ((frot0[nt] + 4) & 7) * 8];
            }
            for (int mt = 0; mt < 2; ++mt) {
                float w = wv[mt][e];
                for (int ks = 0; ks < 2; ++ks) {
                    union { uint4 u; short8 s; } af;
                    float4 a0 = ar[mt][ks][0], a1 = ar[mt][ks][1];
                    af.u.x = pkbf(a0.x * w, a0.y * w);
                    af.u.y = pkbf(a0.z * w, a0.w * w);
                    af.u.z = pkbf(a1.x * w, a1.y * w);
                    af.u.w = pkbf(a1.z * w, a1.w * w);
                    for (int nt = 0; nt < 4; ++nt)
                        comb[mt][nt] = __builtin_amdgcn_mfma_f32_16x16x32_bf16(
                            af.s, bf[nt][ks], comb[mt][nt], 0, 0, 0);
                }
            }
            __syncthreads();   // drain next-DMA (overlapped) + release buf readers
        }
    }

    // epilogue: out = comb + rw0*bet_eff[e0] + rw1*bet_eff[e1], single plain store
    for (int mt = 0; mt < 2; ++mt) {
        for (int ri = 0; ri < 4; ++ri) {
            int row = wm + mt * 16 + qr + ri;
            int tok = rt * 128 + row;
            int es = selE[tok];
            float4 w4 = selW[tok];
            int e0 = es & 255, e1 = es >> 8;
            for (int nt = 0; nt < 4; ++nt) {
                int col = ct * 64 + nt * 16 + mrow;
                float bet = w4.z * wsBet[e0 * OUTL + col] + w4.w * wsBet[e1 * OUTL + col];
                out[(size_t)tok * OUTL + col] = comb[mt][nt][ri] + bet;
            }
        }
    }
}

extern "C" void kernel_launch(void* const* d_in, const int* in_sizes, int n_in,
                              void* d_out, int out_size, void* d_ws, size_t ws_size,
                              hipStream_t stream) {
    const float* x        = (const float*)d_in[0];
    const float* ins      = (const float*)d_in[1];
    const float* gate_w   = (const float*)d_in[2];
    const float* expert_w = (const float*)d_in[3];
    const float* expert_b = (const float*)d_in[4];
    const float* gamma_w  = (const float*)d_in[5];
    const float* beta_w   = (const float*)d_in[6];
    const float* rmod_w   = (const float*)d_in[7];
    float* out = (float*)d_out;

    char* ws = (char*)d_ws;
    float*    wsS    = (float*)(ws + WS_S);
    float*    wsGam  = (float*)(ws + WS_GAM);
    float*    wsRgam = (float*)(ws + WS_RGAM);
    float*    wsBet  = (float*)(ws + WS_BET);
    int*      selE   = (int*)(ws + WS_SELE);
    float4*   selW   = (float4*)(ws + WS_SELW);
    ushort_t* wt     = (ushort_t*)(ws + WS_WT);

    k_stats<<<1, 256, 0, stream>>>(ins, gamma_w, rmod_w, wsS, wsGam, wsRgam);
    k_wt<<<dim3(8, 8, 8), 256, 0, stream>>>(expert_w, wt);
    k_bet<<<dim3(16, 8), 256, 0, stream>>>(ins, gamma_w, beta_w, expert_b, wsBet);
    k_route<<<N_TOK / 16, 256, 0, stream>>>(x, gate_w, wsGam, wsRgam, selE, selW);
    k_gemm<<<512, 256, 0, stream>>>(x, wt, selE, selW, wsBet, out);
}